// Round 20
// baseline (197.629 us; speedup 1.0000x reference)
//
#include <hip/hip_runtime.h>
#include <math.h>

using f32x4  = __attribute__((ext_vector_type(4))) float;
using bf16x8 = __attribute__((ext_vector_type(8))) short;

typedef const __attribute__((address_space(1))) void gas_void;
typedef __attribute__((address_space(3))) void las_void;

__device__ __forceinline__ void gl16(const void* g, void* l) {
    __builtin_amdgcn_global_load_lds((gas_void*)g, (las_void*)l, 16, 0, 0);
}

__device__ __forceinline__ unsigned short f2bf(float f) {
    union { float f; unsigned u; } v; v.f = f;
    unsigned r = v.u + 0x7fffu + ((v.u >> 16) & 1u);   // RNE
    return (unsigned short)(r >> 16);
}
__device__ __forceinline__ float bf2f(unsigned short u) {
    return __uint_as_float(((unsigned)u) << 16);
}

#define VW0() asm volatile("s_waitcnt vmcnt(0)" ::: "memory")
#define BAR() __builtin_amdgcn_s_barrier()

// ---------------- prep: X (NCHW fp32) -> patch-major bf16 Xp[36864][768] ----------------
__global__ void pcl_prep_x(const float* __restrict__ x, unsigned short* __restrict__ xp) {
    int t = threadIdx.x;              // 256
    int wv = t >> 6, l = t & 63;
    int p = blockIdx.x * 4 + wv;      // patch id
    int b = p / 576, n = p % 576;
    int ph = n / 24, pw = n % 24;
    const float* base = x + ((size_t)(b * 3)) * 147456 + (ph * 16) * 384 + pw * 16;
    unsigned* dst = (unsigned*)(xp + (size_t)p * 768);
#pragma unroll
    for (int q = 0; q < 6; ++q) {
        int k = q * 128 + l * 2;
        int c = k >> 8, i = (k >> 4) & 15, j = k & 15;
        const float* s = base + (size_t)c * 147456 + i * 384 + j;
        float2 v = *(const float2*)s;
        unsigned lo = f2bf(v.x), hi = f2bf(v.y);
        dst[q * 64 + l] = lo | (hi << 16);
    }
}

// ---------------- prep: W -> bf16; latents -> row-normalized bf16 ----------------
__global__ void pcl_prep_wl(const float* __restrict__ w,
                            const float* __restrict__ l1, const float* __restrict__ l2,
                            unsigned short* __restrict__ wsW,
                            unsigned short* __restrict__ wsL) {
    int r = blockIdx.x, t = threadIdx.x;   // 2816 x 64
    if (r < 768) {
        const float* src = w + (size_t)r * 768;
        unsigned short* dst = wsW + (size_t)r * 768;
#pragma unroll
        for (int i = 0; i < 12; ++i) dst[t + 64 * i] = f2bf(src[t + 64 * i]);
    } else {
        int lr = r - 768;
        const float* src = (lr < 1024) ? l1 + (size_t)lr * 768 : l2 + (size_t)(lr - 1024) * 768;
        unsigned short* dst = wsL + (size_t)lr * 768;
        float vals[12];
        float s = 0.f;
#pragma unroll
        for (int i = 0; i < 12; ++i) {
            float f = bf2f(f2bf(src[t + 64 * i]));
            vals[i] = f; s += f * f;
        }
#pragma unroll
        for (int off = 32; off; off >>= 1) s += __shfl_xor(s, off, 64);
        float rn = 1.0f / sqrtf(s);
#pragma unroll
        for (int i = 0; i < 12; ++i) dst[t + 64 * i] = f2bf(vals[i] * rn);
    }
}

// ================= K1': conv GEMM 192x96 tiles, 2 blocks/CU (R12 + addr-hoist) ========
#define K1_LDS 81920

__global__ __launch_bounds__(256, 2)
void pcl_k1(const unsigned short* __restrict__ xp,
            const unsigned short* __restrict__ wsW,
            const float* __restrict__ bias,
            unsigned short* __restrict__ pbuf,
            float* __restrict__ rpnp) {
    extern __shared__ char smem[];
    const int t = threadIdx.x, w = t >> 6, l = t & 63;
    const int wg = (blockIdx.x & 7) * 192 + (blockIdx.x >> 3);   // bijective XCD remap
    const int mt = wg >> 3, nt = wg & 7;
    const size_t Mb = (size_t)mt * 192;
    const int Nb = nt * 96;
    const int wm = w >> 1, wn = w & 1;
    const int ir = l >> 3, s2 = (l & 7) ^ ir;
    const int lm = l & 15, lg4 = l >> 4;

    if ((blockIdx.x >> 8) & 1) __builtin_amdgcn_s_setprio(1);   // persistent anti-phase

    // precomputed gl16 source pointers (kt=0) and LDS dst bases (buf0)
    const char* gA[6]; const char* gB[3];
#pragma unroll
    for (int rr = 0; rr < 6; ++rr)
        gA[rr] = (const char*)(xp + (Mb + (w * 6 + rr) * 8 + ir) * 768 + s2 * 8);
#pragma unroll
    for (int rr = 0; rr < 3; ++rr)
        gB[rr] = (const char*)(wsW + (size_t)(Nb + (w * 3 + rr) * 8 + ir) * 768 + s2 * 8);
    char* dA = smem + w * 6144;
    char* dB = smem + 24576 + w * 3072;

    // lane-constant LDS read offsets (row&7 == lm&7 for every fragment row)
    unsigned aO[2], bO[2];
#pragma unroll
    for (int ks = 0; ks < 2; ++ks) {
        unsigned swz = (unsigned)((((ks * 4 + lg4) ^ (lm & 7))) << 4);
        aO[ks] = (unsigned)((wm * 96 + lm) * 128) + swz;
        bO[ks] = 24576u + (unsigned)((wn * 48 + lm) * 128) + swz;
    }

    f32x4 acc[6][3];
#pragma unroll
    for (int m = 0; m < 6; ++m)
#pragma unroll
        for (int nb = 0; nb < 3; ++nb) acc[m][nb] = (f32x4)0.f;

    // prologue: stage tile 0 into buf0
#pragma unroll
    for (int rr = 0; rr < 6; ++rr) gl16(gA[rr], dA + rr * 1024);
#pragma unroll
    for (int rr = 0; rr < 3; ++rr) gl16(gB[rr], dB + rr * 1024);
    VW0(); BAR();

    bf16x8 areg[3][2], breg[3][2];

    auto body = [&](int kt, int CUR, int NXT) {
        if (kt < 11) {
            int koff = (kt + 1) << 7;
#pragma unroll
            for (int rr = 0; rr < 6; ++rr) gl16(gA[rr] + koff, dA + NXT + rr * 1024);
#pragma unroll
            for (int rr = 0; rr < 3; ++rr) gl16(gB[rr] + koff, dB + NXT + rr * 1024);
        }
#pragma unroll
        for (int nb = 0; nb < 3; ++nb)
#pragma unroll
            for (int ks = 0; ks < 2; ++ks)
                breg[nb][ks] = *(const bf16x8*)(smem + CUR + bO[ks] + nb * 2048);
#pragma unroll
        for (int m = 0; m < 3; ++m)
#pragma unroll
            for (int ks = 0; ks < 2; ++ks)
                areg[m][ks] = *(const bf16x8*)(smem + CUR + aO[ks] + m * 2048);
#pragma unroll
        for (int m = 0; m < 3; ++m)
#pragma unroll
            for (int nb = 0; nb < 3; ++nb)
#pragma unroll
                for (int ks = 0; ks < 2; ++ks)
                    acc[m][nb] = __builtin_amdgcn_mfma_f32_16x16x32_bf16(areg[m][ks], breg[nb][ks], acc[m][nb], 0, 0, 0);
#pragma unroll
        for (int m = 0; m < 3; ++m)
#pragma unroll
            for (int ks = 0; ks < 2; ++ks)
                areg[m][ks] = *(const bf16x8*)(smem + CUR + aO[ks] + 6144 + m * 2048);
#pragma unroll
        for (int m = 0; m < 3; ++m)
#pragma unroll
            for (int nb = 0; nb < 3; ++nb)
#pragma unroll
                for (int ks = 0; ks < 2; ++ks)
                    acc[3 + m][nb] = __builtin_amdgcn_mfma_f32_16x16x32_bf16(areg[m][ks], breg[nb][ks], acc[3 + m][nb], 0, 0, 0);
        VW0();
        BAR();
    };

    for (int kp = 0; kp < 6; ++kp) {
        body(2 * kp,     0,     40960);
        body(2 * kp + 1, 40960, 0);
    }

    // ---- epilogue: bias, bf16 P store, partial row sumsq over this block's 96 cols ----
    float rs[6][4];
#pragma unroll
    for (int m = 0; m < 6; ++m)
#pragma unroll
        for (int j = 0; j < 4; ++j) rs[m][j] = 0.f;
#pragma unroll
    for (int nb = 0; nb < 3; ++nb) {
        int d = Nb + wn * 48 + nb * 16 + lm;
        float bv = bias[d];
#pragma unroll
        for (int m = 0; m < 6; ++m) {
            int mh = m / 3, mi = m % 3;
#pragma unroll
            for (int j = 0; j < 4; ++j) {
                int row = wm * 96 + mh * 48 + mi * 16 + lg4 * 4 + j;
                unsigned short h = f2bf(acc[m][nb][j] + bv);
                pbuf[(Mb + row) * 768 + d] = h;
                float fv = bf2f(h);
                rs[m][j] += fv * fv;
            }
        }
    }
#pragma unroll
    for (int m = 0; m < 6; ++m)
#pragma unroll
        for (int j = 0; j < 4; ++j) {
            rs[m][j] += __shfl_xor(rs[m][j], 1);
            rs[m][j] += __shfl_xor(rs[m][j], 2);
            rs[m][j] += __shfl_xor(rs[m][j], 4);
            rs[m][j] += __shfl_xor(rs[m][j], 8);
        }
    __syncthreads();
    float* nrm = (float*)smem;     // [192][2]
    if (lm == 0) {
#pragma unroll
        for (int m = 0; m < 6; ++m) {
            int mh = m / 3, mi = m % 3;
#pragma unroll
            for (int j = 0; j < 4; ++j) {
                int row = wm * 96 + mh * 48 + mi * 16 + lg4 * 4 + j;
                nrm[row * 2 + wn] = rs[m][j];
            }
        }
    }
    __syncthreads();
    if (t < 192) rpnp[(size_t)nt * 36864 + Mb + t] = nrm[t * 2] + nrm[t * 2 + 1];
}

// ---------------- norm: rpn = rsqrt(sum of 8 partials) ----------------
__global__ void pcl_norm(const float* __restrict__ rpnp, float* __restrict__ rpn) {
    int i = blockIdx.x * 256 + threadIdx.x;   // 144 x 256 = 36864
    float s = 0.f;
#pragma unroll
    for (int nt = 0; nt < 8; ++nt) s += rpnp[(size_t)nt * 36864 + i];
    rpn[i] = 1.0f / sqrtf(s);
}

// ================= K2: score GEMM 192x128, 2-phase (R12 + addr-hoist + prio-asym) =====
#define K2_LDS 81920

__global__ __launch_bounds__(256, 2)
void pcl_k2(const unsigned short* __restrict__ pbuf,
            const unsigned short* __restrict__ wsL,
            const float* __restrict__ rpn,
            double* __restrict__ partials) {
    extern __shared__ char smem[];
    const int t = threadIdx.x, w = t >> 6, l = t & 63;
    const int wg = (blockIdx.x & 7) * 384 + (blockIdx.x >> 3);   // bijective XCD remap
    const int mt = wg >> 4, nt = wg & 15;
    const size_t Mb = (size_t)mt * 192;
    const int Nb = nt * 128;
    const int wm = w >> 1, wn = w & 1;
    const int ir = l >> 3, s2 = (l & 7) ^ ir;
    const int lm = l & 15, lg4 = l >> 4;

    if ((blockIdx.x >> 8) & 1) __builtin_amdgcn_s_setprio(1);   // persistent anti-phase

    // precomputed gl16 source pointers (kt=0) and LDS dst bases (buf0)
    const char* gA[6]; const char* gB[4];
#pragma unroll
    for (int rr = 0; rr < 6; ++rr)
        gA[rr] = (const char*)(pbuf + (Mb + (w * 6 + rr) * 8 + ir) * 768 + s2 * 8);
#pragma unroll
    for (int rr = 0; rr < 4; ++rr)
        gB[rr] = (const char*)(wsL + (size_t)(Nb + (w * 4 + rr) * 8 + ir) * 768 + s2 * 8);
    char* dA = smem + w * 6144;
    char* dB = smem + 24576 + w * 4096;

    // lane-constant LDS read offsets (row&7 == lm&7 for every fragment row)
    unsigned aO[2], bO[2];
#pragma unroll
    for (int ks = 0; ks < 2; ++ks) {
        unsigned swz = (unsigned)((((ks * 4 + lg4) ^ (lm & 7))) << 4);
        aO[ks] = (unsigned)((wm * 96 + lm) * 128) + swz;
        bO[ks] = 24576u + (unsigned)((wn * 64 + lm) * 128) + swz;
    }

    f32x4 acc[6][4];
#pragma unroll
    for (int m = 0; m < 6; ++m)
#pragma unroll
        for (int nb = 0; nb < 4; ++nb) acc[m][nb] = (f32x4)0.f;

    // prologue: stage tile 0 into buf0
#pragma unroll
    for (int rr = 0; rr < 6; ++rr) gl16(gA[rr], dA + rr * 1024);
#pragma unroll
    for (int rr = 0; rr < 4; ++rr) gl16(gB[rr], dB + rr * 1024);
    VW0(); BAR();

    bf16x8 areg[3][2], breg[4][2];

    auto body = [&](int kt, int CUR, int NXT) {
        if (kt < 11) {
            int koff = (kt + 1) << 7;
#pragma unroll
            for (int rr = 0; rr < 6; ++rr) gl16(gA[rr] + koff, dA + NXT + rr * 1024);
#pragma unroll
            for (int rr = 0; rr < 4; ++rr) gl16(gB[rr] + koff, dB + NXT + rr * 1024);
        }
#pragma unroll
        for (int nb = 0; nb < 4; ++nb)
#pragma unroll
            for (int ks = 0; ks < 2; ++ks)
                breg[nb][ks] = *(const bf16x8*)(smem + CUR + bO[ks] + nb * 2048);
#pragma unroll
        for (int m = 0; m < 3; ++m)
#pragma unroll
            for (int ks = 0; ks < 2; ++ks)
                areg[m][ks] = *(const bf16x8*)(smem + CUR + aO[ks] + m * 2048);
#pragma unroll
        for (int m = 0; m < 3; ++m)
#pragma unroll
            for (int nb = 0; nb < 4; ++nb)
#pragma unroll
                for (int ks = 0; ks < 2; ++ks)
                    acc[m][nb] = __builtin_amdgcn_mfma_f32_16x16x32_bf16(areg[m][ks], breg[nb][ks], acc[m][nb], 0, 0, 0);
#pragma unroll
        for (int m = 0; m < 3; ++m)
#pragma unroll
            for (int ks = 0; ks < 2; ++ks)
                areg[m][ks] = *(const bf16x8*)(smem + CUR + aO[ks] + 6144 + m * 2048);
#pragma unroll
        for (int m = 0; m < 3; ++m)
#pragma unroll
            for (int nb = 0; nb < 4; ++nb)
#pragma unroll
                for (int ks = 0; ks < 2; ++ks)
                    acc[3 + m][nb] = __builtin_amdgcn_mfma_f32_16x16x32_bf16(areg[m][ks], breg[nb][ks], acc[3 + m][nb], 0, 0, 0);
        VW0();
        BAR();
    };

    for (int kp = 0; kp < 6; ++kp) {
        body(2 * kp,     0,     40960);
        body(2 * kp + 1, 40960, 0);
    }

    // epilogue: exp(2*cos*rpn); whole tile lies in one batch (192 | 576)
    double ssum = 0.0;
#pragma unroll
    for (int m = 0; m < 6; ++m) {
        int mh = m / 3, mi = m % 3;
        int rl = wm * 96 + mh * 48 + mi * 16;
        float rv[4];
#pragma unroll
        for (int j = 0; j < 4; ++j) rv[j] = rpn[Mb + rl + lg4 * 4 + j];
        float es = 0.f;
#pragma unroll
        for (int nb = 0; nb < 4; ++nb)
#pragma unroll
            for (int j = 0; j < 4; ++j)
                es += __expf(2.0f * acc[m][nb][j] * rv[j]);
        ssum += (double)es;
    }
#pragma unroll
    for (int off = 32; off; off >>= 1) ssum += __shfl_down(ssum, off);
    __syncthreads();
    double* red = (double*)smem;
    if (l == 0) red[w] = ssum;
    __syncthreads();
    if (t == 0) {
        double s = 0.0;
#pragma unroll
        for (int i = 0; i < 4; ++i) s += red[i];
        partials[wg] = s;
    }
}

// ---------------- finish: per-batch gather (3 mt x 16 nt), log-ratio, mean --------
__global__ void pcl_finish(const double* __restrict__ partials, float* __restrict__ out) {
    int b = threadIdx.x;   // 64 batches
    double far = 0.0, close = 0.0;
#pragma unroll
    for (int i = 0; i < 3; ++i) {
        int mt = b * 3 + i;
#pragma unroll
        for (int nTile = 0; nTile < 16; ++nTile) {
            double v = partials[mt * 16 + nTile];
            if (nTile < 8) far += v; else close += v;
        }
    }
    double lb = log(far) - log(close);
#pragma unroll
    for (int off = 32; off; off >>= 1) lb += __shfl_down(lb, off);
    if (b == 0) out[0] = (float)(lb * (1.0 / 64.0));
}

extern "C" void kernel_launch(void* const* d_in, const int* in_sizes, int n_in,
                              void* d_out, int out_size, void* d_ws, size_t ws_size,
                              hipStream_t stream) {
    const float* x    = (const float*)d_in[0];
    const float* w    = (const float*)d_in[1];
    const float* bias = (const float*)d_in[2];
    const float* l1   = (const float*)d_in[3];
    const float* l2   = (const float*)d_in[4];
    float* out = (float*)d_out;

    unsigned short* xp   = (unsigned short*)d_ws;                        // 36864*768 bf16 X
    unsigned short* pbuf = (unsigned short*)((char*)d_ws + 56623104);    // 36864*768 bf16 P
    unsigned short* wsW  = (unsigned short*)((char*)d_ws + 113246208);   // 768*768 bf16
    unsigned short* wsL  = (unsigned short*)((char*)d_ws + 114425856);   // 2048*768 bf16
    float* rpnp          = (float*)((char*)d_ws + 117571584);            // 8*36864 f32
    float* rpn           = (float*)((char*)d_ws + 118751232);            // 36864 f32
    double* partials     = (double*)((char*)d_ws + 118898688);           // 3072 f64

    (void)hipFuncSetAttribute((const void*)pcl_k1,
                              hipFuncAttributeMaxDynamicSharedMemorySize, K1_LDS);
    (void)hipFuncSetAttribute((const void*)pcl_k2,
                              hipFuncAttributeMaxDynamicSharedMemorySize, K2_LDS);

    pcl_prep_x<<<9216, 256, 0, stream>>>(x, xp);
    pcl_prep_wl<<<2816, 64, 0, stream>>>(w, l1, l2, wsW, wsL);
    pcl_k1<<<1536, 256, K1_LDS, stream>>>(xp, wsW, bias, pbuf, rpnp);
    pcl_norm<<<144, 256, 0, stream>>>(rpnp, rpn);
    pcl_k2<<<3072, 256, K2_LDS, stream>>>(pbuf, wsL, rpn, partials);
    pcl_finish<<<1, 64, 0, stream>>>(partials, out);
}